// Round 5
// baseline (403.190 us; speedup 1.0000x reference)
//
#include <hip/hip_runtime.h>
#include <math.h>

#define BATCH 32768
#define SEQLEN 200
#define PSTEPS 50
#define HID 32

typedef __attribute__((ext_vector_type(2))) _Float16 half2v;
typedef __attribute__((ext_vector_type(8))) _Float16 half8v;
typedef __attribute__((ext_vector_type(2))) __fp16   fp16x2;   // cvt_pkrtz return type
typedef __attribute__((ext_vector_type(4))) float floatx4;
typedef __attribute__((ext_vector_type(2))) float float2v;

#define EXP2 __builtin_amdgcn_exp2f      // v_exp_f32: 2^x
#define RCPF __builtin_amdgcn_rcpf       // v_rcp_f32
#define PKRTZ __builtin_amdgcn_cvt_pkrtz // v_cvt_pkrtz_f16_f32
#define MED3 __builtin_amdgcn_fmed3f     // v_med3_f32
#define FMA2 __builtin_elementwise_fma   // <2 x float> fma -> v_pk_fma_f32

#define L1C 1.4426950408889634f          // log2(e)
#define L2C 2.8853900817779268f          // 2*log2(e)

union H8 { unsigned int u[4]; half8v h; half2v h2[4]; };
union HU { fp16x2 h; unsigned int u; };

__device__ __forceinline__ unsigned int pk(float a, float b) {
    HU t; t.h = PKRTZ(a, b); return t.u;
}

// R15: TRANSPOSED recurrence — no LDS at all. Compute gates^T = W'.h^T with
// weights as the A operand (row=gate) and h as the B operand (col=batch=m):
// batch stays in-lane across steps. The gate ROWS of W_hh/W_ih/bias are
// permuted at fragment build time by phi(hf,p) = (p>>2)*8 + hf*4 + (p&3) so
// that lane (m,quad)'s D rows (p=quad*4+r, tiles hf) are gates of cells
// quad*8 + hf*4 + r  ==  exactly this lane's own B-fragment k-slots
// (k=quad*8+j) for the next step. The h round-trip through LDS (8 ds_write +
// 2 ds_read + RAW commit latency, 4.1M conflict cycles) is replaced by the
// 4 cvt_pkrtz that build the next B fragment — recurrence fully in registers.
// Same summands at same k positions, A/B roles swapped: bit-identical math.
// Operand layouts (hardware-verified lineage R0-R14): A row=lane&15,
// k=quad*8+j; B col=lane&15, k=quad*8+j; D col=lane&15, row=quad*4+reg.
// Per-cell arithmetic token-for-token R14 (exp2-domain folded weights,
// paired rcp, med3 tanh clamp EXACT, c unclamped, bias hi/lo, decode f-gate
// dead, anti-phase s_sleep stagger, 2 waves/SIMD).
__global__ __launch_bounds__(256, 2)
void lstm_mfma_kernel(const float* __restrict__ hist, const float* __restrict__ W_ih,
                      const float* __restrict__ W_hh, const float* __restrict__ b_ih,
                      const float* __restrict__ b_hh, const float* __restrict__ W_pred,
                      const float* __restrict__ b_pred, float* __restrict__ out)
{
    const int lane = threadIdx.x & 63;
    const int wv   = threadIdx.x >> 6;
    const int m    = lane & 15;
    const int quad = lane >> 4;
    const int elem0 = (blockIdx.x * 4 + wv) * 16;

    // anti-phase: co-resident pair assumed (k, k+256) for 512-block grid
    if ((blockIdx.x >> 8) & 1) __builtin_amdgcn_s_sleep(12);

    // gate-row permutation: phi(hf, m) = phi0 + hf*4
    const int phi0 = ((m >> 2) * 8) + (m & 3);

    // ---- resident weight fragments (f16, exp-scale folded), A-operand side.
    //      tile T = g*2 + hf (g: 0=i,1=f,2=g,3=o) ----
    const float esc[4] = { -L1C, -L1C, L2C, -L1C };   // i,f,g,o exp2-domain scales
    half8v Ah[8], Ax[8];
    #pragma unroll
    for (int T = 0; T < 8; ++T) {
        const int g = T >> 1, hf = T & 1;
        const int grow = g * 32 + phi0 + hf * 4;      // permuted gate row 0..127
        const float sc = esc[g];
        H8 ah;
        #pragma unroll
        for (int jj = 0; jj < 4; ++jj) {
            ah.h2[jj] = (half2v){ (_Float16)(sc * W_hh[grow * HID + quad * 8 + 2 * jj]),
                                  (_Float16)(sc * W_hh[grow * HID + quad * 8 + 2 * jj + 1]) };
        }
        Ah[T] = ah.h;
        H8 ax; ax.u[0] = ax.u[1] = ax.u[2] = ax.u[3] = 0u;
        if (quad == 0) {
            ax.h2[0] = (half2v){ (_Float16)(sc * W_ih[grow * 4 + 0]), (_Float16)(sc * W_ih[grow * 4 + 1]) };
            ax.h2[1] = (half2v){ (_Float16)(sc * W_ih[grow * 4 + 2]), (_Float16)(sc * W_ih[grow * 4 + 3]) };
            float bsum = sc * (b_ih[grow] + b_hh[grow]);
            _Float16 bhi = (_Float16)bsum;
            _Float16 blo = (_Float16)(bsum - (float)bhi);   // bias exact to ~2^-24
            ax.h2[2] = (half2v){ bhi, blo };                // K rows 4,5 (B = 1,1)
        }
        Ax[T] = ax.h;
    }
    const unsigned int one2 = 0x3C003C00u;   // (1.0h, 1.0h)
    const floatx4 zf4 = { 0.f, 0.f, 0.f, 0.f };

    // ---- state: c (f32), h packed f16 B-fragment, h f32 copy for decode ----
    float cst[2][4], hr[2][4];
    #pragma unroll
    for (int hf = 0; hf < 2; ++hf)
        #pragma unroll
        for (int r = 0; r < 4; ++r) { cst[hf][r] = 0.f; hr[hf][r] = 0.f; }
    H8 hb; hb.u[0] = hb.u[1] = hb.u[2] = hb.u[3] = 0u;   // h = 0 packed

    // ---- encode: 200 steps ----
    const float4* xp = (const float4*)(hist + (size_t)(elem0 + m) * (SEQLEN * 4));
    float4 xv = xp[0];
    #pragma unroll 1
    for (int t = 0; t < SEQLEN; ++t) {
        const unsigned int tx0 = pk(xv.x, xv.y), tx1 = pk(xv.z, xv.w);
        H8 bx;
        bx.u[0] = (quad == 0) ? tx0 : 0u;
        bx.u[1] = (quad == 0) ? tx1 : 0u;
        bx.u[2] = (quad == 0) ? one2 : 0u;
        bx.u[3] = 0u;

        const int tn = (t + 1 < SEQLEN) ? t + 1 : SEQLEN - 1;
        float4 xn = xp[tn];                  // prefetch stays in flight

        floatx4 acc[8];
        #pragma unroll
        for (int T = 0; T < 8; ++T) {
            floatx4 a = __builtin_amdgcn_mfma_f32_16x16x32_f16(Ax[T], bx.h, zf4, 0, 0, 0);
            acc[T] = __builtin_amdgcn_mfma_f32_16x16x32_f16(Ah[T], hb.h, a, 0, 0, 0);
        }
        // gates in exp2 domain; cell pairs packed as float2 -> v_pk_* ops.
        // lane (m,quad): acc[2g+hf][r] = gate g of cell quad*8+hf*4+r, batch m.
        H8 nhb;
        #pragma unroll
        for (int hf = 0; hf < 2; ++hf) {
            #pragma unroll
            for (int pr = 0; pr < 2; ++pr) {
                const int r0 = pr * 2, r1 = r0 + 1;
                const float2v ei = { EXP2(acc[0 + hf][r0]), EXP2(acc[0 + hf][r1]) };
                const float2v ef = { EXP2(acc[2 + hf][r0]), EXP2(acc[2 + hf][r1]) };
                const float2v eg = { EXP2(acc[4 + hf][r0]), EXP2(acc[4 + hf][r1]) };
                const float2v eo = { EXP2(acc[6 + hf][r0]), EXP2(acc[6 + hf][r1]) };
                // cn = c/(1+ef) + (eg-1)/((1+ei)(1+eg)) ; rcp shared across pair
                const float2v pf = 1.f + ef;
                const float2v t1 = (1.f + ei) * (1.f + eg);
                const float2v cc = { cst[hf][r0], cst[hf][r1] };
                const float2v num = FMA2(cc, t1, (eg - 1.f) * pf);
                const float2v d  = t1 * pf;                 // <= 2^52 each
                const float   R  = RCPF(d.x * d.y);         // <= 2^104: safe
                const float2v dsw = { d.y, d.x };
                const float2v cn  = num * (R * dsw);
                // tanh input clamp +-12: EXACT (tanh(12)==1.0f in fp32)
                const float2v cna = { MED3(cn.x, -12.f, 12.f), MED3(cn.y, -12.f, 12.f) };
                const float2v ea  = cna * L2C;
                const float2v ec  = { EXP2(ea.x), EXP2(ea.y) };
                const float2v dh  = (1.f + eo) * (1.f + ec);
                const float   Rh  = RCPF(dh.x * dh.y);
                const float2v dhsw = { dh.y, dh.x };
                const float2v hn  = (ec - 1.f) * (Rh * dhsw);

                cst[hf][r0] = cn.x; cst[hf][r1] = cn.y;     // state UNclamped (matches ref)
                hr[hf][r0] = hn.x;  hr[hf][r1] = hn.y;      // f32 copy (decode matvec)
                nhb.u[hf * 2 + pr] = pk(hn.x, hn.y);        // next B fragment slot k=2*(hf*2+pr)
            }
        }
        hb = nhb;
        xv = xn;
    }

    // ---- decode: 50 steps (c reset to 0 -> f-gate dead; tiles 2,3 skipped) ----
    // lane holds cells quad*8 + (hf*4+r) of batch m; flatten j = hf*4+r:
    // wpl[d][j] = W_pred[d][quad*8 + j] — same indexing as the untransposed kernel.
    float wpl[4][8];
    #pragma unroll
    for (int d = 0; d < 4; ++d)
        #pragma unroll
        for (int j = 0; j < 8; ++j) wpl[d][j] = W_pred[d * HID + quad * 8 + j];
    float bp[4] = { b_pred[0], b_pred[1], b_pred[2], b_pred[3] };

    float* op = out + (size_t)(elem0 + m) * (PSTEPS * 4);
    #pragma unroll 1
    for (int p = 0; p < PSTEPS; ++p) {
        float pd[4];
        #pragma unroll
        for (int d = 0; d < 4; ++d) {
            float s = 0.f;
            #pragma unroll
            for (int j = 0; j < 8; ++j) s = fmaf(hr[j >> 2][j & 3], wpl[d][j], s);
            s += __shfl_xor(s, 16);       // reduce across the 4 quads of column m
            s += __shfl_xor(s, 32);
            pd[d] = s + bp[d];
        }
        if (quad == 0) *(float4*)(op + p * 4) = make_float4(pd[0], pd[1], pd[2], pd[3]);

        if (p + 1 < PSTEPS) {
            const unsigned int tx0 = pk(pd[0], pd[1]), tx1 = pk(pd[2], pd[3]);
            H8 bx;
            bx.u[0] = (quad == 0) ? tx0 : 0u;
            bx.u[1] = (quad == 0) ? tx1 : 0u;
            bx.u[2] = (quad == 0) ? one2 : 0u;
            bx.u[3] = 0u;

            floatx4 acc[6];   // tiles 0,1=i ; 4,5=g ; 6,7=o
            #pragma unroll
            for (int nn = 0; nn < 6; ++nn) {
                const int n = (nn < 2) ? nn : nn + 2;
                floatx4 a = __builtin_amdgcn_mfma_f32_16x16x32_f16(Ax[n], bx.h, zf4, 0, 0, 0);
                acc[nn] = __builtin_amdgcn_mfma_f32_16x16x32_f16(Ah[n], hb.h, a, 0, 0, 0);
            }
            H8 nhb;
            #pragma unroll
            for (int hf = 0; hf < 2; ++hf) {
                #pragma unroll
                for (int pr = 0; pr < 2; ++pr) {
                    const int r0 = pr * 2, r1 = r0 + 1;
                    const float2v ei = { EXP2(acc[0 + hf][r0]), EXP2(acc[0 + hf][r1]) };
                    const float2v eg = { EXP2(acc[2 + hf][r0]), EXP2(acc[2 + hf][r1]) };
                    const float2v eo = { EXP2(acc[4 + hf][r0]), EXP2(acc[4 + hf][r1]) };
                    // cn = (eg-1)/((1+ei)(1+eg)) (c==0); |cn|<1
                    const float2v d  = (1.f + ei) * (1.f + eg);
                    const float   R  = RCPF(d.x * d.y);
                    const float2v dsw = { d.y, d.x };
                    const float2v cn  = (eg - 1.f) * (R * dsw);
                    const float2v ea  = cn * L2C;
                    const float2v ec  = { EXP2(ea.x), EXP2(ea.y) };   // ec in [2^-2.9, 2^2.9]
                    const float2v dh  = (1.f + eo) * (1.f + ec);
                    const float   Rh  = RCPF(dh.x * dh.y);
                    const float2v dhsw = { dh.y, dh.x };
                    const float2v hn  = (ec - 1.f) * (Rh * dhsw);

                    hr[hf][r0] = hn.x;  hr[hf][r1] = hn.y;
                    nhb.u[hf * 2 + pr] = pk(hn.x, hn.y);
                }
            }
            hb = nhb;
        }
    }
}

extern "C" void kernel_launch(void* const* d_in, const int* in_sizes, int n_in,
                              void* d_out, int out_size, void* d_ws, size_t ws_size,
                              hipStream_t stream) {
    const float* hist   = (const float*)d_in[0];
    const float* W_ih   = (const float*)d_in[1];
    const float* W_hh   = (const float*)d_in[2];
    const float* b_ih   = (const float*)d_in[3];
    const float* b_hh   = (const float*)d_in[4];
    const float* W_pred = (const float*)d_in[5];
    const float* b_pred = (const float*)d_in[6];
    float* out = (float*)d_out;

    const int blocks = (BATCH / 16) / 4;   // 512 blocks = 2048 waves, 2/SIMD
    lstm_mfma_kernel<<<blocks, 256, 0, stream>>>(hist, W_ih, W_hh, b_ih, b_hh,
                                                 W_pred, b_pred, out);
}

// Round 6
// 399.147 us; speedup vs baseline: 1.0101x; 1.0101x over previous
//
#include <hip/hip_runtime.h>
#include <math.h>

#define BATCH 32768
#define SEQLEN 200
#define PSTEPS 50
#define HID 32
#define LDS_PAD 36   // float row stride 36 -> mild bank aliasing only (m136)

typedef __attribute__((ext_vector_type(2))) _Float16 half2v;
typedef __attribute__((ext_vector_type(8))) _Float16 half8v;
typedef __attribute__((ext_vector_type(2))) __fp16   fp16x2;   // cvt_pkrtz return type
typedef __attribute__((ext_vector_type(4))) float floatx4;
typedef __attribute__((ext_vector_type(2))) float float2v;

#define EXP2 __builtin_amdgcn_exp2f      // v_exp_f32: 2^x
#define RCPF __builtin_amdgcn_rcpf       // v_rcp_f32
#define PKRTZ __builtin_amdgcn_cvt_pkrtz // v_cvt_pkrtz_f16_f32
#define MED3 __builtin_amdgcn_fmed3f     // v_med3_f32
#define FMA2 __builtin_elementwise_fma   // <2 x float> fma -> v_pk_fma_f32

#define L1C 1.4426950408889634f          // log2(e)
#define L2C 2.8853900817779268f          // 2*log2(e)

union H8 { unsigned int u[4]; half8v h; half2v h2[4]; };
union HU { fp16x2 h; unsigned int u; };

__device__ __forceinline__ unsigned int pk(float a, float b) {
    HU t; t.h = PKRTZ(a, b); return t.u;
}

// R16: cell-half wave split, WITH THE R11/R12 BUG FIXED. The split wave owns
// acc[4] indexed by GATE g (i,f,g,o), but R11/R12's gate loop was copied
// from the unsplit kernel and indexed acc[0+hf],acc[2+hf],... over an hf
// loop — reading the f-gate as the i-gate (and OOB in decode). The exchange
// machinery itself was sound. Fixed here: single-hf gate loop over
// acc[g][r] (r = batch row), cst[4], h-write column hfw*16+m.
//
// Structure: one 16-batch group = TWO waves (block=128). Wave hfw owns gate
// tiles n = 2*g + hfw  ==  cells hfw*16+m (m = lane&15 = D gate-col).
// Per-wave work HALVES (4 MFMA-pairs, 24 trans/lane-step, half gate VALU);
// wave count doubles to 4096 = 4/SIMD; chip-wide issue unchanged; latency
// hiding doubles — attacks the ~35% un-hidden stall R13/R15 established.
// h exchanged through double-buffered hbuf: read [p], write [p^1], barrier,
// flip. x-prefetch issued at loop top (syncthreads drains vmcnt).
// Per-cell arithmetic is token-for-token R14 (exp2-domain folded weights,
// float2-packed pairs across batch rows r0,r1, shared rcps, med3 tanh clamp
// EXACT, c unclamped, bias hi/lo, decode f-gate dead): absmax must equal
// 9.766e-4 exactly.
// D layout: row(batch)=quad*4+reg, col(gate)=lane&15; A: m=lane&15, k=quad*8+j.
__global__ __launch_bounds__(128, 4)
void lstm_mfma_kernel(const float* __restrict__ hist, const float* __restrict__ W_ih,
                      const float* __restrict__ W_hh, const float* __restrict__ b_ih,
                      const float* __restrict__ b_hh, const float* __restrict__ W_pred,
                      const float* __restrict__ b_pred, float* __restrict__ out)
{
    const int lane = threadIdx.x & 63;
    const int hfw  = threadIdx.x >> 6;   // 0: cells 0..15, 1: cells 16..31
    const int m    = lane & 15;
    const int quad = lane >> 4;
    const int elem0 = blockIdx.x * 16;

    __shared__ __align__(16) float hbuf[2][16][LDS_PAD];   // double-buffered h

    // ---- resident weight fragments (f16, exp-scale folded); this wave owns
    //      tiles n = 2*g + hfw, stored indexed by g ----
    const float esc[4] = { -L1C, -L1C, L2C, -L1C };   // i,f,g,o exp2-domain scales
    half8v Bh[4], B2[4];
    #pragma unroll
    for (int g = 0; g < 4; ++g) {
        const int gc = (2 * g + hfw) * 16 + m;        // gate row 0..127
        const float sc = esc[g];
        H8 bh;
        #pragma unroll
        for (int jj = 0; jj < 4; ++jj) {
            bh.h2[jj] = (half2v){ (_Float16)(sc * W_hh[gc * HID + quad * 8 + 2 * jj]),
                                  (_Float16)(sc * W_hh[gc * HID + quad * 8 + 2 * jj + 1]) };
        }
        Bh[g] = bh.h;
        H8 b2; b2.u[0] = b2.u[1] = b2.u[2] = b2.u[3] = 0u;
        if (quad == 0) {
            b2.h2[0] = (half2v){ (_Float16)(sc * W_ih[gc * 4 + 0]), (_Float16)(sc * W_ih[gc * 4 + 1]) };
            b2.h2[1] = (half2v){ (_Float16)(sc * W_ih[gc * 4 + 2]), (_Float16)(sc * W_ih[gc * 4 + 3]) };
            float bsum = sc * (b_ih[gc] + b_hh[gc]);
            _Float16 bhi = (_Float16)bsum;
            _Float16 blo = (_Float16)(bsum - (float)bhi);   // bias exact to ~2^-24
            b2.h2[2] = (half2v){ bhi, blo };                // K rows 4,5 (A = 1,1)
        }
        B2[g] = b2.h;
    }
    const unsigned int one2 = 0x3C003C00u;   // (1.0h, 1.0h)
    const floatx4 zf4 = { 0.f, 0.f, 0.f, 0.f };

    // ---- init h = 0 (both buffers, each wave its 16 columns), c = 0 ----
    // lane's cells: batch quad*4+r (r=0..3), cell hfw*16+m
    float cst[4];
    #pragma unroll
    for (int r = 0; r < 4; ++r) {
        cst[r] = 0.f;
        hbuf[0][quad * 4 + r][hfw * 16 + m] = 0.f;
        hbuf[1][quad * 4 + r][hfw * 16 + m] = 0.f;
    }
    __syncthreads();

    // ---- encode: 200 steps ----
    int p = 0;
    const float4* xp = (const float4*)(hist + (size_t)(elem0 + m) * (SEQLEN * 4));
    float4 xv = xp[0];
    #pragma unroll 1
    for (int t = 0; t < SEQLEN; ++t) {
        // prefetch first: barrier below drains vmcnt(0); whole body in flight
        const int tn = (t + 1 < SEQLEN) ? t + 1 : SEQLEN - 1;
        float4 xn = xp[tn];

        float4 h0 = *(const float4*)&hbuf[p][m][quad * 8];
        float4 h1 = *(const float4*)&hbuf[p][m][quad * 8 + 4];
        H8 ahu;
        ahu.u[0] = pk(h0.x, h0.y); ahu.u[1] = pk(h0.z, h0.w);
        ahu.u[2] = pk(h1.x, h1.y); ahu.u[3] = pk(h1.z, h1.w);
        const half8v ah = ahu.h;

        const unsigned int tx0 = pk(xv.x, xv.y), tx1 = pk(xv.z, xv.w);
        H8 a2u;
        a2u.u[0] = (quad == 0) ? tx0 : 0u;
        a2u.u[1] = (quad == 0) ? tx1 : 0u;
        a2u.u[2] = (quad == 0) ? one2 : 0u;
        a2u.u[3] = 0u;
        const half8v a2 = a2u.h;

        floatx4 acc[4];                      // acc[g]: g = 0:i 1:f 2:g 3:o
        #pragma unroll
        for (int g = 0; g < 4; ++g) {
            floatx4 a = __builtin_amdgcn_mfma_f32_16x16x32_f16(a2, B2[g], zf4, 0, 0, 0);
            acc[g] = __builtin_amdgcn_mfma_f32_16x16x32_f16(ah, Bh[g], a, 0, 0, 0);
        }
        // gates in exp2 domain; (r0,r1) batch-row pairs packed float2, shared rcps.
        // FIX vs R12: acc indexed by g directly, no hf loop.
        #pragma unroll
        for (int pr = 0; pr < 2; ++pr) {
            const int r0 = pr * 2, r1 = r0 + 1;
            const float2v ei = { EXP2(acc[0][r0]), EXP2(acc[0][r1]) };
            const float2v ef = { EXP2(acc[1][r0]), EXP2(acc[1][r1]) };
            const float2v eg = { EXP2(acc[2][r0]), EXP2(acc[2][r1]) };
            const float2v eo = { EXP2(acc[3][r0]), EXP2(acc[3][r1]) };
            // cn = c/(1+ef) + (eg-1)/((1+ei)(1+eg)) ; rcp shared across pair
            const float2v pf = 1.f + ef;
            const float2v t1 = (1.f + ei) * (1.f + eg);
            const float2v cc = { cst[r0], cst[r1] };
            const float2v num = FMA2(cc, t1, (eg - 1.f) * pf);
            const float2v d  = t1 * pf;                 // <= 2^52 each
            const float   R  = RCPF(d.x * d.y);         // <= 2^104: safe
            const float2v dsw = { d.y, d.x };
            const float2v cn  = num * (R * dsw);
            // tanh input clamp +-12: EXACT (tanh(12)==1.0f in fp32)
            const float2v cna = { MED3(cn.x, -12.f, 12.f), MED3(cn.y, -12.f, 12.f) };
            const float2v ea  = cna * L2C;
            const float2v ec  = { EXP2(ea.x), EXP2(ea.y) };
            const float2v dh  = (1.f + eo) * (1.f + ec);
            const float   Rh  = RCPF(dh.x * dh.y);
            const float2v dhsw = { dh.y, dh.x };
            const float2v hn  = (ec - 1.f) * (Rh * dhsw);

            cst[r0] = cn.x; cst[r1] = cn.y;             // state UNclamped (matches ref)
            hbuf[p ^ 1][quad * 4 + r0][hfw * 16 + m] = hn.x;   // FIX: col = hfw*16+m
            hbuf[p ^ 1][quad * 4 + r1][hfw * 16 + m] = hn.y;
        }
        __syncthreads();
        p ^= 1;
        xv = xn;
    }

    // ---- decode: 50 steps (c reset to 0 -> f-gate dead; tile g=1 skipped) ----
    float wp[4][8];
    #pragma unroll
    for (int d = 0; d < 4; ++d)
        #pragma unroll
        for (int j = 0; j < 8; ++j) wp[d][j] = W_pred[d * HID + quad * 8 + j];
    float bp[4] = { b_pred[0], b_pred[1], b_pred[2], b_pred[3] };

    float* op = out + (size_t)(elem0 + m) * (PSTEPS * 4);
    #pragma unroll 1
    for (int ps = 0; ps < PSTEPS; ++ps) {
        float4 h0 = *(const float4*)&hbuf[p][m][quad * 8];
        float4 h1 = *(const float4*)&hbuf[p][m][quad * 8 + 4];
        const float hv[8] = { h0.x, h0.y, h0.z, h0.w, h1.x, h1.y, h1.z, h1.w };

        // both waves compute pd (both need it as next-step x input)
        float pd[4];
        #pragma unroll
        for (int d = 0; d < 4; ++d) {
            float s = 0.f;
            #pragma unroll
            for (int j = 0; j < 8; ++j) s = fmaf(hv[j], wp[d][j], s);
            s += __shfl_xor(s, 16);
            s += __shfl_xor(s, 32);
            pd[d] = s + bp[d];
        }
        if (hfw == 0 && quad == 0) *(float4*)(op + ps * 4) = make_float4(pd[0], pd[1], pd[2], pd[3]);

        if (ps + 1 < PSTEPS) {
            H8 ahu;
            ahu.u[0] = pk(hv[0], hv[1]); ahu.u[1] = pk(hv[2], hv[3]);
            ahu.u[2] = pk(hv[4], hv[5]); ahu.u[3] = pk(hv[6], hv[7]);
            const half8v ah = ahu.h;
            const unsigned int tx0 = pk(pd[0], pd[1]), tx1 = pk(pd[2], pd[3]);
            H8 a2u;
            a2u.u[0] = (quad == 0) ? tx0 : 0u;
            a2u.u[1] = (quad == 0) ? tx1 : 0u;
            a2u.u[2] = (quad == 0) ? one2 : 0u;
            a2u.u[3] = 0u;
            const half8v a2 = a2u.h;

            floatx4 acc3[3];   // acc3[0]=i (g=0), acc3[1]=g (g=2), acc3[2]=o (g=3)
            {
                floatx4 a;
                a = __builtin_amdgcn_mfma_f32_16x16x32_f16(a2, B2[0], zf4, 0, 0, 0);
                acc3[0] = __builtin_amdgcn_mfma_f32_16x16x32_f16(ah, Bh[0], a, 0, 0, 0);
                a = __builtin_amdgcn_mfma_f32_16x16x32_f16(a2, B2[2], zf4, 0, 0, 0);
                acc3[1] = __builtin_amdgcn_mfma_f32_16x16x32_f16(ah, Bh[2], a, 0, 0, 0);
                a = __builtin_amdgcn_mfma_f32_16x16x32_f16(a2, B2[3], zf4, 0, 0, 0);
                acc3[2] = __builtin_amdgcn_mfma_f32_16x16x32_f16(ah, Bh[3], a, 0, 0, 0);
            }
            // FIX vs R12: direct gate indexing, no hf loop
            #pragma unroll
            for (int pr = 0; pr < 2; ++pr) {
                const int r0 = pr * 2, r1 = r0 + 1;
                const float2v ei = { EXP2(acc3[0][r0]), EXP2(acc3[0][r1]) };
                const float2v eg = { EXP2(acc3[1][r0]), EXP2(acc3[1][r1]) };
                const float2v eo = { EXP2(acc3[2][r0]), EXP2(acc3[2][r1]) };
                // cn = (eg-1)/((1+ei)(1+eg)) (c==0); |cn|<1
                const float2v d  = (1.f + ei) * (1.f + eg);
                const float   R  = RCPF(d.x * d.y);
                const float2v dsw = { d.y, d.x };
                const float2v cn  = (eg - 1.f) * (R * dsw);
                const float2v ea  = cn * L2C;
                const float2v ec  = { EXP2(ea.x), EXP2(ea.y) };   // ec in [2^-2.9, 2^2.9]
                const float2v dh  = (1.f + eo) * (1.f + ec);
                const float   Rh  = RCPF(dh.x * dh.y);
                const float2v dhsw = { dh.y, dh.x };
                const float2v hn  = (ec - 1.f) * (Rh * dhsw);

                hbuf[p ^ 1][quad * 4 + r0][hfw * 16 + m] = hn.x;
                hbuf[p ^ 1][quad * 4 + r1][hfw * 16 + m] = hn.y;
            }
            __syncthreads();
            p ^= 1;
        }
    }
}

extern "C" void kernel_launch(void* const* d_in, const int* in_sizes, int n_in,
                              void* d_out, int out_size, void* d_ws, size_t ws_size,
                              hipStream_t stream) {
    const float* hist   = (const float*)d_in[0];
    const float* W_ih   = (const float*)d_in[1];
    const float* W_hh   = (const float*)d_in[2];
    const float* b_ih   = (const float*)d_in[3];
    const float* b_hh   = (const float*)d_in[4];
    const float* W_pred = (const float*)d_in[5];
    const float* b_pred = (const float*)d_in[6];
    float* out = (float*)d_out;

    const int blocks = BATCH / 16;   // 2048 blocks x 128 thr = 4096 waves, 4/SIMD
    lstm_mfma_kernel<<<blocks, 128, 0, stream>>>(hist, W_ih, W_hh, b_ih, b_hh,
                                                 W_pred, b_pred, out);
}

// Round 7
// 367.769 us; speedup vs baseline: 1.0963x; 1.0853x over previous
//
#include <hip/hip_runtime.h>
#include <math.h>

#define BATCH 32768
#define SEQLEN 200
#define PSTEPS 50
#define HID 32
#define LDS_PAD 36   // float row stride 36 -> mild bank aliasing only (m136)

typedef __attribute__((ext_vector_type(2))) _Float16 half2v;
typedef __attribute__((ext_vector_type(8))) _Float16 half8v;
typedef __attribute__((ext_vector_type(2))) __fp16   fp16x2;   // cvt_pkrtz return type
typedef __attribute__((ext_vector_type(4))) float floatx4;
typedef __attribute__((ext_vector_type(2))) float float2v;

#define EXP2 __builtin_amdgcn_exp2f      // v_exp_f32: 2^x
#define RCPF __builtin_amdgcn_rcpf       // v_rcp_f32
#define PKRTZ __builtin_amdgcn_cvt_pkrtz // v_cvt_pkrtz_f16_f32
#define MED3 __builtin_amdgcn_fmed3f     // v_med3_f32
#define FMA2 __builtin_elementwise_fma   // <2 x float> fma -> v_pk_fma_f32

#define L1C 1.4426950408889634f          // log2(e)
#define L2C 2.8853900817779268f          // 2*log2(e)

union H8 { unsigned int u[4]; half8v h; half2v h2[4]; };
union HU { fp16x2 h; unsigned int u; };

__device__ __forceinline__ unsigned int pk(float a, float b) {
    HU t; t.h = PKRTZ(a, b); return t.u;
}

// R17 = R14 (the measured optimum of the concurrency-structure space:
// one wave = private 16-batch group, private LDS h-region, no barriers,
// 2 waves/SIMD, float2-packed gate math, no lgkmcnt drain) + two
// zero-semantic-risk scheduling aids:
//  1. encode loop unrolled 2x: each iteration's independent head (x pack,
//     a2 build, prefetch, loop arith) fills the previous iteration's
//     gate-math/MFMA stall shadows; halves branch overhead. Serial h
//     dependence unchanged — this only widens the scheduler's window.
//  2. MFMA tiles issued evens-first {0,2,4,6,1,3,5,7}: the hf=0 gate burst
//     needs acc[0,2,4,6]; issuing them first starts the VALU burst ~4
//     MFMA-latencies earlier, overlapping odd tiles' execution.
// No arithmetic change anywhere: absmax must equal 9.766e-4 exactly.
// Concurrency map (measured): (2/SIMD,16b/wave)=284us < (4/SIMD,cell-split)
// =315 < (1/SIMD,2x16b)=375/312. Re-slicing loses to duplication+sync.
// C layout: row(batch)=quad*4+reg, col(gate)=lane&15; A: m=lane&15, k=quad*8+j.
__global__ __launch_bounds__(256, 2)
void lstm_mfma_kernel(const float* __restrict__ hist, const float* __restrict__ W_ih,
                      const float* __restrict__ W_hh, const float* __restrict__ b_ih,
                      const float* __restrict__ b_hh, const float* __restrict__ W_pred,
                      const float* __restrict__ b_pred, float* __restrict__ out)
{
    const int lane = threadIdx.x & 63;
    const int wv   = threadIdx.x >> 6;
    const int m    = lane & 15;
    const int quad = lane >> 4;
    const int elem0 = (blockIdx.x * 4 + wv) * 16;

    // anti-phase: co-resident pair assumed (k, k+256) for 512-block grid
    if ((blockIdx.x >> 8) & 1) __builtin_amdgcn_s_sleep(12);

    __shared__ __align__(16) float h_lds_all[4][16][LDS_PAD];
    float (*hl)[LDS_PAD] = h_lds_all[wv];    // per-wave region: no __syncthreads ever

    // ---- resident weight fragments (f16, exp-scale folded; tiles 0,1=i 2,3=f 4,5=g 6,7=o) ----
    const float esc[4] = { -L1C, -L1C, L2C, -L1C };   // i,f,g,o exp2-domain scales
    half8v Bh[8], B2[8];
    #pragma unroll
    for (int n = 0; n < 8; ++n) {
        const int gc = n * 16 + m;           // gate row 0..127
        const float sc = esc[n >> 1];
        H8 bh;
        #pragma unroll
        for (int jj = 0; jj < 4; ++jj) {
            bh.h2[jj] = (half2v){ (_Float16)(sc * W_hh[gc * HID + quad * 8 + 2 * jj]),
                                  (_Float16)(sc * W_hh[gc * HID + quad * 8 + 2 * jj + 1]) };
        }
        Bh[n] = bh.h;
        H8 b2; b2.u[0] = b2.u[1] = b2.u[2] = b2.u[3] = 0u;
        if (quad == 0) {
            b2.h2[0] = (half2v){ (_Float16)(sc * W_ih[gc * 4 + 0]), (_Float16)(sc * W_ih[gc * 4 + 1]) };
            b2.h2[1] = (half2v){ (_Float16)(sc * W_ih[gc * 4 + 2]), (_Float16)(sc * W_ih[gc * 4 + 3]) };
            float bsum = sc * (b_ih[gc] + b_hh[gc]);
            _Float16 bhi = (_Float16)bsum;
            _Float16 blo = (_Float16)(bsum - (float)bhi);   // bias exact to ~2^-24
            b2.h2[2] = (half2v){ bhi, blo };                // K rows 4,5 (A = 1,1)
        }
        B2[n] = b2.h;
    }
    const unsigned int one2 = 0x3C003C00u;   // (1.0h, 1.0h)
    const floatx4 zf4 = { 0.f, 0.f, 0.f, 0.f };

    // ---- init h = 0 (LDS), c = 0 (regs) ----
    float cst[2][4];
    #pragma unroll
    for (int hf = 0; hf < 2; ++hf)
        #pragma unroll
        for (int r = 0; r < 4; ++r) { cst[hf][r] = 0.f; hl[quad * 4 + r][hf * 16 + m] = 0.f; }
    // no drain needed: DS pipe is in-order per wave

    // ---- encode: 200 steps, unrolled 2x for scheduling window ----
    const float4* xp = (const float4*)(hist + (size_t)(elem0 + m) * (SEQLEN * 4));
    float4 xv = xp[0];
    #pragma unroll 2
    for (int t = 0; t < SEQLEN; ++t) {
        float4 h0 = *(const float4*)&hl[m][quad * 8];
        float4 h1 = *(const float4*)&hl[m][quad * 8 + 4];
        H8 ahu;
        ahu.u[0] = pk(h0.x, h0.y); ahu.u[1] = pk(h0.z, h0.w);
        ahu.u[2] = pk(h1.x, h1.y); ahu.u[3] = pk(h1.z, h1.w);
        const half8v ah = ahu.h;

        const unsigned int tx0 = pk(xv.x, xv.y), tx1 = pk(xv.z, xv.w);
        H8 a2u;
        a2u.u[0] = (quad == 0) ? tx0 : 0u;
        a2u.u[1] = (quad == 0) ? tx1 : 0u;
        a2u.u[2] = (quad == 0) ? one2 : 0u;
        a2u.u[3] = 0u;
        const half8v a2 = a2u.h;

        const int tn = (t + 1 < SEQLEN) ? t + 1 : SEQLEN - 1;
        float4 xn = xp[tn];                  // prefetch stays in flight

        // evens first: hf=0's acc tiles (0,2,4,6) complete earliest
        floatx4 acc[8];
        #pragma unroll
        for (int nn = 0; nn < 8; ++nn) {
            const int n = (nn < 4) ? (nn * 2) : ((nn - 4) * 2 + 1);
            floatx4 a = __builtin_amdgcn_mfma_f32_16x16x32_f16(a2, B2[n], zf4, 0, 0, 0);
            acc[n] = __builtin_amdgcn_mfma_f32_16x16x32_f16(ah, Bh[n], a, 0, 0, 0);
        }
        // gates arrive in exp2 domain; cell pairs packed as float2 -> v_pk_* ops
        #pragma unroll
        for (int hf = 0; hf < 2; ++hf) {
            #pragma unroll
            for (int pr = 0; pr < 2; ++pr) {
                const int r0 = pr * 2, r1 = r0 + 1;
                const float2v ei = { EXP2(acc[0 + hf][r0]), EXP2(acc[0 + hf][r1]) };
                const float2v ef = { EXP2(acc[2 + hf][r0]), EXP2(acc[2 + hf][r1]) };
                const float2v eg = { EXP2(acc[4 + hf][r0]), EXP2(acc[4 + hf][r1]) };
                const float2v eo = { EXP2(acc[6 + hf][r0]), EXP2(acc[6 + hf][r1]) };
                // cn = c/(1+ef) + (eg-1)/((1+ei)(1+eg)) ; rcp shared across pair
                const float2v pf = 1.f + ef;
                const float2v t1 = (1.f + ei) * (1.f + eg);
                const float2v cc = { cst[hf][r0], cst[hf][r1] };
                const float2v num = FMA2(cc, t1, (eg - 1.f) * pf);
                const float2v d  = t1 * pf;                 // <= 2^52 each
                const float   R  = RCPF(d.x * d.y);         // <= 2^104: safe
                const float2v dsw = { d.y, d.x };
                const float2v cn  = num * (R * dsw);
                // tanh input clamp +-12: EXACT (tanh(12)==1.0f in fp32)
                const float2v cna = { MED3(cn.x, -12.f, 12.f), MED3(cn.y, -12.f, 12.f) };
                const float2v ea  = cna * L2C;
                const float2v ec  = { EXP2(ea.x), EXP2(ea.y) };
                const float2v dh  = (1.f + eo) * (1.f + ec);
                const float   Rh  = RCPF(dh.x * dh.y);
                const float2v dhsw = { dh.y, dh.x };
                const float2v hn  = (ec - 1.f) * (Rh * dhsw);

                cst[hf][r0] = cn.x; cst[hf][r1] = cn.y;     // state UNclamped (matches ref)
                hl[quad * 4 + r0][hf * 16 + m] = hn.x;
                hl[quad * 4 + r1][hf * 16 + m] = hn.y;
            }
        }
        // no lgkmcnt drain: DS in-order per wave; compiler can't hoist the
        // may-aliasing next-step reads above these writes
        xv = xn;
    }

    // ---- decode: 50 steps (c reset to 0 -> f-gate dead; tiles 2,3 skipped) ----
    float wp[4][8];
    #pragma unroll
    for (int d = 0; d < 4; ++d)
        #pragma unroll
        for (int j = 0; j < 8; ++j) wp[d][j] = W_pred[d * HID + quad * 8 + j];
    float bp[4] = { b_pred[0], b_pred[1], b_pred[2], b_pred[3] };

    float* op = out + (size_t)(elem0 + m) * (PSTEPS * 4);
    #pragma unroll 1
    for (int p = 0; p < PSTEPS; ++p) {
        float4 h0 = *(const float4*)&hl[m][quad * 8];
        float4 h1 = *(const float4*)&hl[m][quad * 8 + 4];
        const float hv[8] = { h0.x, h0.y, h0.z, h0.w, h1.x, h1.y, h1.z, h1.w };

        float pd[4];
        #pragma unroll
        for (int d = 0; d < 4; ++d) {
            float s = 0.f;
            #pragma unroll
            for (int j = 0; j < 8; ++j) s = fmaf(hv[j], wp[d][j], s);
            s += __shfl_xor(s, 16);
            s += __shfl_xor(s, 32);
            pd[d] = s + bp[d];
        }
        if (quad == 0) *(float4*)(op + p * 4) = make_float4(pd[0], pd[1], pd[2], pd[3]);

        if (p + 1 < PSTEPS) {
            H8 ahu;
            ahu.u[0] = pk(hv[0], hv[1]); ahu.u[1] = pk(hv[2], hv[3]);
            ahu.u[2] = pk(hv[4], hv[5]); ahu.u[3] = pk(hv[6], hv[7]);
            const half8v ah = ahu.h;
            const unsigned int tx0 = pk(pd[0], pd[1]), tx1 = pk(pd[2], pd[3]);
            H8 a2u;
            a2u.u[0] = (quad == 0) ? tx0 : 0u;
            a2u.u[1] = (quad == 0) ? tx1 : 0u;
            a2u.u[2] = (quad == 0) ? one2 : 0u;
            a2u.u[3] = 0u;
            const half8v a2 = a2u.h;

            floatx4 acc[6];   // tiles 0,1=i ; 4,5=g ; 6,7=o
            #pragma unroll
            for (int nn = 0; nn < 6; ++nn) {
                const int n = (nn < 2) ? nn : nn + 2;
                floatx4 a = __builtin_amdgcn_mfma_f32_16x16x32_f16(a2, B2[n], zf4, 0, 0, 0);
                acc[nn] = __builtin_amdgcn_mfma_f32_16x16x32_f16(ah, Bh[n], a, 0, 0, 0);
            }
            #pragma unroll
            for (int hf = 0; hf < 2; ++hf) {
                #pragma unroll
                for (int pr = 0; pr < 2; ++pr) {
                    const int r0 = pr * 2, r1 = r0 + 1;
                    const float2v ei = { EXP2(acc[0 + hf][r0]), EXP2(acc[0 + hf][r1]) };
                    const float2v eg = { EXP2(acc[2 + hf][r0]), EXP2(acc[2 + hf][r1]) };
                    const float2v eo = { EXP2(acc[4 + hf][r0]), EXP2(acc[4 + hf][r1]) };
                    // cn = (eg-1)/((1+ei)(1+eg)) (c==0); |cn|<1
                    const float2v d  = (1.f + ei) * (1.f + eg);
                    const float   R  = RCPF(d.x * d.y);
                    const float2v dsw = { d.y, d.x };
                    const float2v cn  = (eg - 1.f) * (R * dsw);
                    const float2v ea  = cn * L2C;
                    const float2v ec  = { EXP2(ea.x), EXP2(ea.y) };   // ec in [2^-2.9, 2^2.9]
                    const float2v dh  = (1.f + eo) * (1.f + ec);
                    const float   Rh  = RCPF(dh.x * dh.y);
                    const float2v dhsw = { dh.y, dh.x };
                    const float2v hn  = (ec - 1.f) * (Rh * dhsw);

                    hl[quad * 4 + r0][hf * 16 + m] = hn.x;
                    hl[quad * 4 + r1][hf * 16 + m] = hn.y;
                }
            }
            // no lgkmcnt drain (DS in-order per wave)
        }
    }
}

extern "C" void kernel_launch(void* const* d_in, const int* in_sizes, int n_in,
                              void* d_out, int out_size, void* d_ws, size_t ws_size,
                              hipStream_t stream) {
    const float* hist   = (const float*)d_in[0];
    const float* W_ih   = (const float*)d_in[1];
    const float* W_hh   = (const float*)d_in[2];
    const float* b_ih   = (const float*)d_in[3];
    const float* b_hh   = (const float*)d_in[4];
    const float* W_pred = (const float*)d_in[5];
    const float* b_pred = (const float*)d_in[6];
    float* out = (float*)d_out;

    const int blocks = (BATCH / 16) / 4;   // 512 blocks = 2048 waves, 2/SIMD
    lstm_mfma_kernel<<<blocks, 256, 0, stream>>>(hist, W_ih, W_hh, b_ih, b_hh,
                                                 W_pred, b_pred, out);
}